// Round 5
// baseline (701.251 us; speedup 1.0000x reference)
//
#include <hip/hip_runtime.h>

// ---------------------------------------------------------------------------
// HardConstrainedMLP: 3-layer MLP -> 100 relaxed DR iterations -> P_eq(P_box)
//   AAT = A A^T + 1e-6 I = L L^T,  G = L^{-1}A (64x256),  b' = L^{-1} b_row
//   corr(w) = (w@G^T - b')@G ;  z += 1.7*(clip(z) - z - corr(2*clip(z)-z))
// R5: 2 barriers/iter (w-exchange is wave-private: MV1 reads only its own
//     d-band, which the same wave's MV2 wrote -> loop-end barrier deleted);
//     med3 clamps; v_pk_fma_f32 update; fast prep; block phase-stagger.
// ---------------------------------------------------------------------------

typedef float f32x2 __attribute__((ext_vector_type(2)));
typedef float f32x4 __attribute__((ext_vector_type(4)));
typedef float f32x16 __attribute__((ext_vector_type(16)));
typedef unsigned u32x4 __attribute__((ext_vector_type(4)));
typedef short short8 __attribute__((ext_vector_type(8)));

__device__ __forceinline__ unsigned pack_hi(float a, float b) {
  // (bf16bits(b) << 16) | bf16bits(a)
  return __builtin_amdgcn_perm(__float_as_uint(b), __float_as_uint(a), 0x07060302u);
}
__device__ __forceinline__ float trunch(float x) {
  return __uint_as_float(__float_as_uint(x) & 0xFFFF0000u);
}
__device__ __forceinline__ f32x2 pk_fma(f32x2 a, f32x2 b, f32x2 c) {
  f32x2 d;
  asm("v_pk_fma_f32 %0, %1, %2, %3" : "=v"(d) : "v"(a), "v"(b), "v"(c));
  return d;
}
__device__ __forceinline__ f32x2 pk_fma_negc(f32x2 a, f32x2 b, f32x2 c) {
  f32x2 d;
  asm("v_pk_fma_f32 %0, %1, %2, %3 neg_lo:[0,0,1] neg_hi:[0,0,1]"
      : "=v"(d) : "v"(a), "v"(b), "v"(c));
  return d;
}
__device__ __forceinline__ f32x2 pk_sub(f32x2 a, f32x2 b) {
  f32x2 d;
  asm("v_pk_add_f32 %0, %1, %2 neg_lo:[0,1] neg_hi:[0,1]"
      : "=v"(d) : "v"(a), "v"(b));
  return d;
}
__device__ __forceinline__ float med3(float x, float lo, float hi) {
  return __builtin_amdgcn_fmed3f(x, lo, hi);
}
__device__ __forceinline__ void split2x4(f32x4 a, f32x4 b, short8& hi, short8& lo) {
  union { unsigned u[4]; short8 v; } H, L;
  H.u[0] = pack_hi(a[0], a[1]); H.u[1] = pack_hi(a[2], a[3]);
  H.u[2] = pack_hi(b[0], b[1]); H.u[3] = pack_hi(b[2], b[3]);
  f32x2 l0 = pk_sub((f32x2){a[0], a[1]}, (f32x2){trunch(a[0]), trunch(a[1])});
  f32x2 l1 = pk_sub((f32x2){a[2], a[3]}, (f32x2){trunch(a[2]), trunch(a[3])});
  f32x2 l2 = pk_sub((f32x2){b[0], b[1]}, (f32x2){trunch(b[0]), trunch(b[1])});
  f32x2 l3 = pk_sub((f32x2){b[2], b[3]}, (f32x2){trunch(b[2]), trunch(b[3])});
  L.u[0] = pack_hi(l0[0], l0[1]); L.u[1] = pack_hi(l1[0], l1[1]);
  L.u[2] = pack_hi(l2[0], l2[1]); L.u[3] = pack_hi(l3[0], l3[1]);
  hi = H.v; lo = L.v;
}
__device__ __forceinline__ f32x4 mfma16(short8 a, short8 b, f32x4 c) {
  return __builtin_amdgcn_mfma_f32_16x16x32_bf16(a, b, c, 0, 0, 0);
}
__device__ __forceinline__ f32x16 mfma32(short8 a, short8 b, f32x16 c) {
  return __builtin_amdgcn_mfma_f32_32x32x16_bf16(a, b, c, 0, 0, 0);
}

// ---------------- P1: AAT, Cholesky L, Linv, G = Linv @ A -------------------
__global__ __launch_bounds__(512) void prep_kernel(const float* __restrict__ A,
                                                   float* __restrict__ G_out,
                                                   float* __restrict__ LinvT) {
  __shared__ float As[64 * 260];
  __shared__ float T[64 * 65];
  __shared__ float Xi[64 * 65];  // Linv
  const int t = threadIdx.x;

  for (int q = 0; q < 8; ++q) {
    int f = 4 * (t + 512 * q);
    f32x4 v = *(const f32x4*)&A[f];
    int m = f >> 8, d = f & 255;
    *(f32x4*)&As[m * 260 + d] = v;
  }
  __syncthreads();

  for (int q = 0; q < 8; ++q) {
    int f = t + 512 * q;
    int i = f >> 6, j = f & 63;
    float s = 0.f;
    for (int d = 0; d < 256; d += 4) {
      f32x4 xa = *(const f32x4*)&As[i * 260 + d];
      f32x4 xb = *(const f32x4*)&As[j * 260 + d];
      s += xa[0] * xb[0] + xa[1] * xb[1] + xa[2] * xb[2] + xa[3] * xb[3];
    }
    if (i == j) s += 1e-6f;
    T[i * 65 + j] = s;
  }
  __syncthreads();

  if (t < 64) {
    // wave-lockstep Cholesky (lower); lanes 0..63 in one wave
    for (int j = 0; j < 64; ++j) {
      float dj = sqrtf(T[j * 65 + j]);
      float lij = 0.f;
      if (t == j) T[j * 65 + j] = dj;
      if (t > j) { lij = T[t * 65 + j] / dj; T[t * 65 + j] = lij; }
      for (int k = j + 1; k <= t; ++k)
        T[t * 65 + k] -= lij * T[k * 65 + j];
    }
    // Linv: lane t solves L x = e_t (column t)
    for (int i = 0; i < 64; ++i) {
      float s = (i == t) ? 1.f : 0.f;
      for (int j = t; j < i; ++j) s -= T[i * 65 + j] * Xi[j * 65 + t];
      Xi[i * 65 + t] = (i >= t) ? s / T[i * 65 + i] : 0.f;
    }
    for (int i = 0; i < 64; ++i) LinvT[t * 64 + i] = Xi[i * 65 + t];
  }
  __syncthreads();

  // G = Linv @ A: lane-parallel over rows i, wave-uniform broadcast As reads
  {
    const int i = t & 63;    // G row
    const int grp = t >> 6;  // wave id 0..7
    float xrow[64];
#pragma unroll
    for (int j = 0; j < 64; ++j) xrow[j] = Xi[i * 65 + j];
    for (int c = 0; c < 4; ++c) {
      const int d0 = 8 * grp + 64 * c;
      float acc[8] = {};
#pragma unroll
      for (int j = 0; j < 64; ++j) {
        f32x4 a0 = *(const f32x4*)&As[j * 260 + d0];
        f32x4 a1 = *(const f32x4*)&As[j * 260 + d0 + 4];
        float x = xrow[j];
        acc[0] += x * a0[0]; acc[1] += x * a0[1];
        acc[2] += x * a0[2]; acc[3] += x * a0[3];
        acc[4] += x * a1[0]; acc[5] += x * a1[1];
        acc[6] += x * a1[2]; acc[7] += x * a1[3];
      }
      *(f32x4*)&G_out[i * 256 + d0] = (f32x4){acc[0], acc[1], acc[2], acc[3]};
      *(f32x4*)&G_out[i * 256 + d0 + 4] = (f32x4){acc[4], acc[5], acc[6], acc[7]};
    }
  }
}

// ---------------- MLP / bp: fp32 tiled GEMM, 64x128 tile -------------------
__global__ __launch_bounds__(256) void gemm64(const float* __restrict__ X,
                                              const float* __restrict__ W,
                                              const float* __restrict__ bias,
                                              float* __restrict__ Y,
                                              int N, int K, int relu) {
  __shared__ float Xs[8][68];
  __shared__ float Ws[8][132];
  const int t = threadIdx.x;
  const int row0 = blockIdx.x * 64, n0 = blockIdx.y * 128;
  const int ty = t >> 4, tx = t & 15;
  const int xr = t >> 2, xk = (t & 3) * 2;
  const int wk = t >> 5, wn = (t & 31) * 4;
  float acc[4][8] = {};
  for (int kc = 0; kc < K; kc += 8) {
    float2 xv = *(const float2*)&X[(size_t)(row0 + xr) * K + kc + xk];
    f32x4 wv4 = {0.f, 0.f, 0.f, 0.f};
    if (n0 + wn + 4 <= N) {
      wv4 = *(const f32x4*)&W[(size_t)(kc + wk) * N + n0 + wn];
    } else {
#pragma unroll
      for (int e = 0; e < 4; ++e)
        if (n0 + wn + e < N) wv4[e] = W[(size_t)(kc + wk) * N + n0 + wn + e];
    }
    __syncthreads();
    Xs[xk][xr] = xv.x;
    Xs[xk + 1][xr] = xv.y;
    *(f32x4*)&Ws[wk][wn] = wv4;
    __syncthreads();
#pragma unroll
    for (int k = 0; k < 8; ++k) {
      f32x4 a = *(const f32x4*)&Xs[k][ty * 4];
      f32x4 b0 = *(const f32x4*)&Ws[k][tx * 8];
      f32x4 b1 = *(const f32x4*)&Ws[k][tx * 8 + 4];
#pragma unroll
      for (int i = 0; i < 4; ++i) {
        acc[i][0] += a[i] * b0[0]; acc[i][1] += a[i] * b0[1];
        acc[i][2] += a[i] * b0[2]; acc[i][3] += a[i] * b0[3];
        acc[i][4] += a[i] * b1[0]; acc[i][5] += a[i] * b1[1];
        acc[i][6] += a[i] * b1[2]; acc[i][7] += a[i] * b1[3];
      }
    }
  }
#pragma unroll
  for (int i = 0; i < 4; ++i) {
    int row = row0 + ty * 4 + i;
#pragma unroll
    for (int jj = 0; jj < 2; ++jj) {
      int c0 = n0 + tx * 8 + jj * 4;
      if (c0 >= N) continue;
      f32x4 v;
#pragma unroll
      for (int e = 0; e < 4; ++e) {
        float bv = bias ? bias[min(c0 + e, N - 1)] : 0.f;
        v[e] = acc[i][4 * jj + e] + bv;
        if (relu) v[e] = fmaxf(v[e], 0.f);
      }
      if (c0 + 4 <= N) {
        *(f32x4*)&Y[(size_t)row * N + c0] = v;
      } else {
#pragma unroll
        for (int e = 0; e < 4; ++e)
          if (c0 + e < N) Y[(size_t)row * N + c0 + e] = v[e];
      }
    }
  }
}

// ---------------- ITER: fused 100x DR on MFMA ------------------------------
// 512 blocks x 256 thr (4 waves), 32 rows/block, 2 blocks/CU.
// Per iter: MV1 (w-read: OWN d-band, no barrier needed) -> bar -> RED ->
// bar -> MV2+update+w-write (own band) -> loop. 2 barriers/iter.
__global__ __launch_bounds__(256) __attribute__((amdgpu_waves_per_eu(2, 2)))
void iter_kernel(const float* __restrict__ y0,
                 const float* __restrict__ Gg,
                 const float* __restrict__ bpg,
                 const float* __restrict__ lb,
                 const float* __restrict__ ub,
                 const int* __restrict__ n_iter_p,
                 float* __restrict__ out) {
  __shared__ __align__(16) float wbuf[32 * 256];     // 32 KB [row][d] f32, granule-XOR
  __shared__ __align__(16) float part[4 * 32 * 68];  // 34 KB [kq][row][m]
  __shared__ __align__(16) unsigned rs[2 * 32 * 32]; // 8 KB [plane][row][32u32], XOR

  const int t = threadIdx.x, wv = t >> 6, lane = t & 63;
  const int l31 = lane & 31, h = lane >> 5;   // 32x32 lane mapping
  const int lhi = lane >> 4, llo = lane & 15; // 16x16 lane mapping
  const int R0 = blockIdx.x * 32;
  const int n_iter = n_iter_p[0];

  // ---- MV1 A-frags (32x32): GA[mt][ks] = G[32mt + l31][64wv + 16ks + 8h + j]
  short8 GAh[2][4], GAl[2][4];
#pragma unroll
  for (int mt = 0; mt < 2; ++mt)
#pragma unroll
    for (int ks = 0; ks < 4; ++ks) {
      const float* gp = &Gg[(32 * mt + l31) * 256 + 64 * wv + 16 * ks + 8 * h];
      split2x4(*(const f32x4*)gp, *(const f32x4*)(gp + 4), GAh[mt][ks], GAl[mt][ks]);
    }
  // ---- MV2 A-frags (16x16): GB[td][ks2] = G[32ks2 + 8lhi + j][64wv + 16td + llo]
  short8 GBh[4][2], GBl[4][2];
#pragma unroll
  for (int td = 0; td < 4; ++td)
#pragma unroll
    for (int ks2 = 0; ks2 < 2; ++ks2) {
      f32x4 fa, fb;
#pragma unroll
      for (int j = 0; j < 4; ++j) {
        fa[j] = Gg[(32 * ks2 + 8 * lhi + j) * 256 + 64 * wv + 16 * td + llo];
        fb[j] = Gg[(32 * ks2 + 8 * lhi + 4 + j) * 256 + 64 * wv + 16 * td + llo];
      }
      split2x4(fa, fb, GBh[td][ks2], GBl[td][ks2]);
    }

  // ---- bounds (z layout) / b' (reduce layout) ----
  f32x4 lbr[4], ubr[4];
#pragma unroll
  for (int td = 0; td < 4; ++td) {
    lbr[td] = *(const f32x4*)&lb[64 * wv + 16 * td + 4 * lhi];
    ubr[td] = *(const f32x4*)&ub[64 * wv + 16 * td + 4 * lhi];
  }
  const int rrow = t >> 3, m8 = (t & 7) * 8;
  f32x4 bpr0 = *(const f32x4*)&bpg[(R0 + rrow) * 64 + m8];
  f32x4 bpr1 = *(const f32x4*)&bpg[(R0 + rrow) * 64 + m8 + 4];

  // ---- precomputed LDS byte addresses ----
  int waddr[2][4];  // w-write: row = 16tr+llo, granule = (16wv+4td+lhi)^(row&7)
  {
    int r3 = llo & 7;
#pragma unroll
    for (int tr = 0; tr < 2; ++tr)
#pragma unroll
      for (int td = 0; td < 4; ++td)
        waddr[tr][td] = (16 * tr + llo) * 1024 + 16 * (((16 * wv + 4 * td + lhi) ^ r3));
  }
  int raddr[4];  // MV1 w-read: row = l31, granule = (16wv + 4ks + 2h)^(l31&7)
  {
    int r3 = l31 & 7;
#pragma unroll
    for (int ks = 0; ks < 4; ++ks)
      raddr[ks] = l31 * 1024 + 16 * ((16 * wv + 4 * ks + 2 * h) ^ r3);
  }
  const int pbase = ((wv * 32 + l31) * 68 + 4 * h) * 4;  // partial store base
  const int prd = (rrow * 68 + m8) * 4;                  // reduce read base
  const int rwr = rrow * 128 + 16 * ((t & 7) ^ (rrow & 7));  // rs write
  int rrd[2][2];  // MV2 rs read
  {
    int r3 = llo & 7;
#pragma unroll
    for (int tr = 0; tr < 2; ++tr)
#pragma unroll
      for (int ks2 = 0; ks2 < 2; ++ks2)
        rrd[tr][ks2] = (16 * tr + llo) * 128 + 16 * ((4 * ks2 + lhi) ^ r3);
  }

  // ---- z init + first w ----
  f32x4 z[4][2];
#pragma unroll
  for (int tr = 0; tr < 2; ++tr)
#pragma unroll
    for (int td = 0; td < 4; ++td) {
      f32x4 v = *(const f32x4*)&y0[(R0 + 16 * tr + llo) * 256 + 64 * wv + 16 * td + 4 * lhi];
      z[td][tr] = v;
      f32x4 wq;
#pragma unroll
      for (int e = 0; e < 4; ++e) {
        float p = med3(v[e], lbr[td][e], ubr[td][e]);
        wq[e] = (n_iter == 0) ? p : fmaf(2.f, p, -v[e]);
      }
      *(f32x4*)((char*)wbuf + waddr[tr][td]) = wq;
    }
  __syncthreads();

  // phase-stagger the two co-resident blocks toward anti-alignment
  if (blockIdx.x & 1) __builtin_amdgcn_s_sleep(32);

  for (int it = 0; it <= n_iter; ++it) {
    // ---- MV1: partial r^T = G @ w^T over this wave's own k-quarter ----
    f32x16 acc0 = {}, acc1 = {};
#pragma unroll
    for (int ks = 0; ks < 4; ++ks) {
      f32x4 f0 = *(const f32x4*)((const char*)wbuf + raddr[ks]);
      f32x4 f1 = *(const f32x4*)((const char*)wbuf + (raddr[ks] ^ 16));
      short8 Bh, Bl;
      split2x4(f0, f1, Bh, Bl);
      __builtin_amdgcn_s_setprio(1);
      acc0 = mfma32(GAh[0][ks], Bh, acc0);
      acc0 = mfma32(GAh[0][ks], Bl, acc0);
      acc0 = mfma32(GAl[0][ks], Bh, acc0);
      acc1 = mfma32(GAh[1][ks], Bh, acc1);
      acc1 = mfma32(GAh[1][ks], Bl, acc1);
      acc1 = mfma32(GAl[1][ks], Bh, acc1);
      __builtin_amdgcn_s_setprio(0);
    }
#pragma unroll
    for (int u = 0; u < 4; ++u) {
      f32x4 q0 = {acc0[4 * u], acc0[4 * u + 1], acc0[4 * u + 2], acc0[4 * u + 3]};
      f32x4 q1 = {acc1[4 * u], acc1[4 * u + 1], acc1[4 * u + 2], acc1[4 * u + 3]};
      *(f32x4*)((char*)part + (pbase + 32 * u)) = q0;
      *(f32x4*)((char*)part + (pbase + 32 * u + 128)) = q1;
    }
    __syncthreads();

    // ---- reduce 4 k-partials, -b', pack to bf16 hi/lo planes ----
    {
      const char* pb = (const char*)part + prd;
      f32x4 s0 = *(const f32x4*)pb;
      f32x4 s1 = *(const f32x4*)(pb + 16);
      s0 += *(const f32x4*)(pb + 8704);  s1 += *(const f32x4*)(pb + 8720);
      s0 += *(const f32x4*)(pb + 17408); s1 += *(const f32x4*)(pb + 17424);
      s0 += *(const f32x4*)(pb + 26112); s1 += *(const f32x4*)(pb + 26128);
      s0 -= bpr0; s1 -= bpr1;
      u32x4 hi4 = {pack_hi(s0[0], s0[1]), pack_hi(s0[2], s0[3]),
                   pack_hi(s1[0], s1[1]), pack_hi(s1[2], s1[3])};
      f32x2 l0 = pk_sub((f32x2){s0[0], s0[1]}, (f32x2){trunch(s0[0]), trunch(s0[1])});
      f32x2 l1 = pk_sub((f32x2){s0[2], s0[3]}, (f32x2){trunch(s0[2]), trunch(s0[3])});
      f32x2 l2 = pk_sub((f32x2){s1[0], s1[1]}, (f32x2){trunch(s1[0]), trunch(s1[1])});
      f32x2 l3 = pk_sub((f32x2){s1[2], s1[3]}, (f32x2){trunch(s1[2]), trunch(s1[3])});
      u32x4 lo4 = {pack_hi(l0[0], l0[1]), pack_hi(l1[0], l1[1]),
                   pack_hi(l2[0], l2[1]), pack_hi(l3[0], l3[1])};
      *(u32x4*)((char*)rs + rwr) = hi4;
      *(u32x4*)((char*)rs + (rwr + 4096)) = lo4;
    }
    __syncthreads();

    // ---- MV2: corr^T = G^T @ r^T (16x16), fused z-update / stores ----
    // NOTE: no barrier after this phase — w-write targets this wave's own
    // d-band, read only by this wave's next MV1 (DS ops are wave-in-order).
#pragma unroll
    for (int tr = 0; tr < 2; ++tr) {
      short8 Rh[2], Rl[2];
#pragma unroll
      for (int ks2 = 0; ks2 < 2; ++ks2) {
        Rh[ks2] = *(const short8*)((const char*)rs + rrd[tr][ks2]);
        Rl[ks2] = *(const short8*)((const char*)rs + (rrd[tr][ks2] + 4096));
      }
      f32x4 c[4];
      __builtin_amdgcn_s_setprio(1);
#pragma unroll
      for (int td = 0; td < 4; ++td) {
        f32x4 cc = {};
        cc = mfma16(GBh[td][0], Rh[0], cc);
        cc = mfma16(GBh[td][0], Rl[0], cc);
        cc = mfma16(GBl[td][0], Rh[0], cc);
        cc = mfma16(GBh[td][1], Rh[1], cc);
        cc = mfma16(GBh[td][1], Rl[1], cc);
        cc = mfma16(GBl[td][1], Rh[1], cc);
        c[td] = cc;
      }
      __builtin_amdgcn_s_setprio(0);

      if (it < n_iter) {
        const bool nextlast = (it == n_iter - 1);
#pragma unroll
        for (int td = 0; td < 4; ++td) {
          f32x4 zz = z[td][tr], zn, wq;
          float p0 = med3(zz[0], lbr[td][0], ubr[td][0]);
          float p1 = med3(zz[1], lbr[td][1], ubr[td][1]);
          float p2 = med3(zz[2], lbr[td][2], ubr[td][2]);
          float p3 = med3(zz[3], lbr[td][3], ubr[td][3]);
          const f32x2 om = {1.7f, 1.7f}, two = {2.f, 2.f};
          f32x2 za = {zz[0], zz[1]}, zb = {zz[2], zz[3]};
          f32x2 ta = pk_sub(pk_sub((f32x2){p0, p1}, za), (f32x2){c[td][0], c[td][1]});
          f32x2 tb = pk_sub(pk_sub((f32x2){p2, p3}, zb), (f32x2){c[td][2], c[td][3]});
          f32x2 zna = pk_fma(om, ta, za);
          f32x2 znb = pk_fma(om, tb, zb);
          zn = (f32x4){zna[0], zna[1], znb[0], znb[1]};
          f32x2 pna = {med3(zna[0], lbr[td][0], ubr[td][0]),
                       med3(zna[1], lbr[td][1], ubr[td][1])};
          f32x2 pnb = {med3(znb[0], lbr[td][2], ubr[td][2]),
                       med3(znb[1], lbr[td][3], ubr[td][3])};
          if (nextlast) {
            wq = (f32x4){pna[0], pna[1], pnb[0], pnb[1]};  // w = p on final pass
          } else {
            f32x2 wa = pk_fma_negc(two, pna, zna);
            f32x2 wb = pk_fma_negc(two, pnb, znb);
            wq = (f32x4){wa[0], wa[1], wb[0], wb[1]};
          }
          z[td][tr] = zn;
          *(f32x4*)((char*)wbuf + waddr[tr][td]) = wq;
        }
      } else {
#pragma unroll
        for (int td = 0; td < 4; ++td) {
          f32x4 zz = z[td][tr], o;
#pragma unroll
          for (int e = 0; e < 4; ++e) {
            float p = med3(zz[e], lbr[td][e], ubr[td][e]);
            o[e] = p - c[td][e];
          }
          *(f32x4*)&out[(R0 + 16 * tr + llo) * 256 + 64 * wv + 16 * td + 4 * lhi] = o;
        }
      }
    }
  }
}

// ---------------------------------------------------------------------------
extern "C" void kernel_launch(void* const* d_in, const int* in_sizes, int n_in,
                              void* d_out, int out_size, void* d_ws, size_t ws_size,
                              hipStream_t stream) {
  (void)in_sizes; (void)n_in; (void)out_size; (void)ws_size;
  const float* x  = (const float*)d_in[0];
  const float* bM = (const float*)d_in[1];
  const float* W1 = (const float*)d_in[2];
  const float* b1 = (const float*)d_in[3];
  const float* W2 = (const float*)d_in[4];
  const float* b2 = (const float*)d_in[5];
  const float* W3 = (const float*)d_in[6];
  const float* b3 = (const float*)d_in[7];
  const float* A  = (const float*)d_in[8];
  const float* lb = (const float*)d_in[9];
  const float* ub = (const float*)d_in[10];
  const int* n_iter = (const int*)d_in[11];
  float* out = (float*)d_out;

  float* ws = (float*)d_ws;
  float* y     = ws;                    // 16384*256
  float* h1    = ws;                    // 16384*200 (overlays y; dead before y)
  float* h2    = y + 16384 * 256;       // 16384*200
  float* bp    = h2 + 16384 * 200;      // 16384*64
  float* G     = bp + 16384 * 64;       // 64*256
  float* LinvT = G + 64 * 256;          // 64*64

  hipLaunchKernelGGL(prep_kernel, dim3(1), dim3(512), 0, stream, A, G, LinvT);
  hipLaunchKernelGGL(gemm64, dim3(256, 1), dim3(256), 0, stream, bM, LinvT, (const float*)nullptr, bp, 64, 64, 0);
  hipLaunchKernelGGL(gemm64, dim3(256, 2), dim3(256), 0, stream, x,  W1, b1, h1, 200, 256, 1);
  hipLaunchKernelGGL(gemm64, dim3(256, 2), dim3(256), 0, stream, h1, W2, b2, h2, 200, 200, 1);
  hipLaunchKernelGGL(gemm64, dim3(256, 2), dim3(256), 0, stream, h2, W3, b3, y,  256, 200, 0);
  hipLaunchKernelGGL(iter_kernel, dim3(512), dim3(256), 0, stream, y, G, bp, lb, ub, n_iter, out);
}

// Round 6
// 695.170 us; speedup vs baseline: 1.0087x; 1.0087x over previous
//
#include <hip/hip_runtime.h>

// ---------------------------------------------------------------------------
// HardConstrainedMLP: 3-layer MLP -> 100 relaxed DR iterations -> P_eq(P_box)
//   AAT = A A^T + 1e-6 I = L L^T,  G = L^{-1}A (64x256),  b' = L^{-1} b_row
//   corr(w) = (w@G^T - b')@G ;  z += 1.7*(clip(z) - z - corr(2*clip(z)-z))
// R6: w-exchange moved from LDS to registers — MV1's B-frag is built from the
//     z register tile via ds_swizzle lane^16 (wbuf deleted, -16 b128/thr/iter);
//     w computed on-the-fly from z in MV1 (no W state). pk inline-asm reverted
//     (R5 spill cause). 2 barriers/iter. LDS 42 KB, 2 blocks/CU.
// ---------------------------------------------------------------------------

typedef float f32x4 __attribute__((ext_vector_type(4)));
typedef float f32x16 __attribute__((ext_vector_type(16)));
typedef unsigned u32x4 __attribute__((ext_vector_type(4)));
typedef short short8 __attribute__((ext_vector_type(8)));

__device__ __forceinline__ unsigned pack_hi(float a, float b) {
  // (bf16bits(b) << 16) | bf16bits(a)
  return __builtin_amdgcn_perm(__float_as_uint(b), __float_as_uint(a), 0x07060302u);
}
__device__ __forceinline__ float trunch(float x) {
  return __uint_as_float(__float_as_uint(x) & 0xFFFF0000u);
}
__device__ __forceinline__ float med3(float x, float lo, float hi) {
  return __builtin_amdgcn_fmed3f(x, lo, hi);
}
__device__ __forceinline__ void split2x4(f32x4 a, f32x4 b, short8& hi, short8& lo) {
  union { unsigned u[4]; short8 v; } H, L;
  H.u[0] = pack_hi(a[0], a[1]); H.u[1] = pack_hi(a[2], a[3]);
  H.u[2] = pack_hi(b[0], b[1]); H.u[3] = pack_hi(b[2], b[3]);
  float l0 = a[0] - trunch(a[0]), l1 = a[1] - trunch(a[1]);
  float l2 = a[2] - trunch(a[2]), l3 = a[3] - trunch(a[3]);
  float l4 = b[0] - trunch(b[0]), l5 = b[1] - trunch(b[1]);
  float l6 = b[2] - trunch(b[2]), l7 = b[3] - trunch(b[3]);
  L.u[0] = pack_hi(l0, l1); L.u[1] = pack_hi(l2, l3);
  L.u[2] = pack_hi(l4, l5); L.u[3] = pack_hi(l6, l7);
  hi = H.v; lo = L.v;
}
__device__ __forceinline__ f32x4 mfma16(short8 a, short8 b, f32x4 c) {
  return __builtin_amdgcn_mfma_f32_16x16x32_bf16(a, b, c, 0, 0, 0);
}
__device__ __forceinline__ f32x16 mfma32(short8 a, short8 b, f32x16 c) {
  return __builtin_amdgcn_mfma_f32_32x32x16_bf16(a, b, c, 0, 0, 0);
}

// ---------------- P1: AAT, Cholesky L, Linv, G = Linv @ A -------------------
__global__ __launch_bounds__(512) void prep_kernel(const float* __restrict__ A,
                                                   float* __restrict__ G_out,
                                                   float* __restrict__ LinvT) {
  __shared__ float As[64 * 260];
  __shared__ float T[64 * 65];
  __shared__ float Xi[64 * 65];  // Linv
  const int t = threadIdx.x;

  for (int q = 0; q < 8; ++q) {
    int f = 4 * (t + 512 * q);
    f32x4 v = *(const f32x4*)&A[f];
    int m = f >> 8, d = f & 255;
    *(f32x4*)&As[m * 260 + d] = v;
  }
  __syncthreads();

  for (int q = 0; q < 8; ++q) {
    int f = t + 512 * q;
    int i = f >> 6, j = f & 63;
    float s = 0.f;
    for (int d = 0; d < 256; d += 4) {
      f32x4 xa = *(const f32x4*)&As[i * 260 + d];
      f32x4 xb = *(const f32x4*)&As[j * 260 + d];
      s += xa[0] * xb[0] + xa[1] * xb[1] + xa[2] * xb[2] + xa[3] * xb[3];
    }
    if (i == j) s += 1e-6f;
    T[i * 65 + j] = s;
  }
  __syncthreads();

  if (t < 64) {
    // wave-lockstep Cholesky (lower); lanes 0..63 in one wave
    for (int j = 0; j < 64; ++j) {
      float dj = sqrtf(T[j * 65 + j]);
      float lij = 0.f;
      if (t == j) T[j * 65 + j] = dj;
      if (t > j) { lij = T[t * 65 + j] / dj; T[t * 65 + j] = lij; }
      for (int k = j + 1; k <= t; ++k)
        T[t * 65 + k] -= lij * T[k * 65 + j];
    }
    // Linv: lane t solves L x = e_t (column t)
    for (int i = 0; i < 64; ++i) {
      float s = (i == t) ? 1.f : 0.f;
      for (int j = t; j < i; ++j) s -= T[i * 65 + j] * Xi[j * 65 + t];
      Xi[i * 65 + t] = (i >= t) ? s / T[i * 65 + i] : 0.f;
    }
    for (int i = 0; i < 64; ++i) LinvT[t * 64 + i] = Xi[i * 65 + t];
  }
  __syncthreads();

  // G = Linv @ A: lane-parallel over rows i, wave-uniform broadcast As reads
  {
    const int i = t & 63;    // G row
    const int grp = t >> 6;  // wave id 0..7
    float xrow[64];
#pragma unroll
    for (int j = 0; j < 64; ++j) xrow[j] = Xi[i * 65 + j];
    for (int c = 0; c < 4; ++c) {
      const int d0 = 8 * grp + 64 * c;
      float acc[8] = {};
#pragma unroll
      for (int j = 0; j < 64; ++j) {
        f32x4 a0 = *(const f32x4*)&As[j * 260 + d0];
        f32x4 a1 = *(const f32x4*)&As[j * 260 + d0 + 4];
        float x = xrow[j];
        acc[0] += x * a0[0]; acc[1] += x * a0[1];
        acc[2] += x * a0[2]; acc[3] += x * a0[3];
        acc[4] += x * a1[0]; acc[5] += x * a1[1];
        acc[6] += x * a1[2]; acc[7] += x * a1[3];
      }
      *(f32x4*)&G_out[i * 256 + d0] = (f32x4){acc[0], acc[1], acc[2], acc[3]};
      *(f32x4*)&G_out[i * 256 + d0 + 4] = (f32x4){acc[4], acc[5], acc[6], acc[7]};
    }
  }
}

// ---------------- MLP / bp: fp32 tiled GEMM, 64x128 tile -------------------
__global__ __launch_bounds__(256) void gemm64(const float* __restrict__ X,
                                              const float* __restrict__ W,
                                              const float* __restrict__ bias,
                                              float* __restrict__ Y,
                                              int N, int K, int relu) {
  __shared__ float Xs[8][68];
  __shared__ float Ws[8][132];
  const int t = threadIdx.x;
  const int row0 = blockIdx.x * 64, n0 = blockIdx.y * 128;
  const int ty = t >> 4, tx = t & 15;
  const int xr = t >> 2, xk = (t & 3) * 2;
  const int wk = t >> 5, wn = (t & 31) * 4;
  float acc[4][8] = {};
  for (int kc = 0; kc < K; kc += 8) {
    float2 xv = *(const float2*)&X[(size_t)(row0 + xr) * K + kc + xk];
    f32x4 wv4 = {0.f, 0.f, 0.f, 0.f};
    if (n0 + wn + 4 <= N) {
      wv4 = *(const f32x4*)&W[(size_t)(kc + wk) * N + n0 + wn];
    } else {
#pragma unroll
      for (int e = 0; e < 4; ++e)
        if (n0 + wn + e < N) wv4[e] = W[(size_t)(kc + wk) * N + n0 + wn + e];
    }
    __syncthreads();
    Xs[xk][xr] = xv.x;
    Xs[xk + 1][xr] = xv.y;
    *(f32x4*)&Ws[wk][wn] = wv4;
    __syncthreads();
#pragma unroll
    for (int k = 0; k < 8; ++k) {
      f32x4 a = *(const f32x4*)&Xs[k][ty * 4];
      f32x4 b0 = *(const f32x4*)&Ws[k][tx * 8];
      f32x4 b1 = *(const f32x4*)&Ws[k][tx * 8 + 4];
#pragma unroll
      for (int i = 0; i < 4; ++i) {
        acc[i][0] += a[i] * b0[0]; acc[i][1] += a[i] * b0[1];
        acc[i][2] += a[i] * b0[2]; acc[i][3] += a[i] * b0[3];
        acc[i][4] += a[i] * b1[0]; acc[i][5] += a[i] * b1[1];
        acc[i][6] += a[i] * b1[2]; acc[i][7] += a[i] * b1[3];
      }
    }
  }
#pragma unroll
  for (int i = 0; i < 4; ++i) {
    int row = row0 + ty * 4 + i;
#pragma unroll
    for (int jj = 0; jj < 2; ++jj) {
      int c0 = n0 + tx * 8 + jj * 4;
      if (c0 >= N) continue;
      f32x4 v;
#pragma unroll
      for (int e = 0; e < 4; ++e) {
        float bv = bias ? bias[min(c0 + e, N - 1)] : 0.f;
        v[e] = acc[i][4 * jj + e] + bv;
        if (relu) v[e] = fmaxf(v[e], 0.f);
      }
      if (c0 + 4 <= N) {
        *(f32x4*)&Y[(size_t)row * N + c0] = v;
      } else {
#pragma unroll
        for (int e = 0; e < 4; ++e)
          if (c0 + e < N) Y[(size_t)row * N + c0 + e] = v[e];
      }
    }
  }
}

// ---------------- ITER: fused 100x DR on MFMA ------------------------------
// 512 blocks x 256 thr (4 waves), 32 rows/block, 2 blocks/CU.
// Per iter: MV1 (w built IN REGISTERS from z via ds_swizzle lane^16) ->
// part st -> bar -> reduce -> rs st -> bar -> MV2 + z-update. 2 barriers.
__global__ __launch_bounds__(256) __attribute__((amdgpu_waves_per_eu(2, 2)))
void iter_kernel(const float* __restrict__ y0,
                 const float* __restrict__ Gg,
                 const float* __restrict__ bpg,
                 const float* __restrict__ lb,
                 const float* __restrict__ ub,
                 const int* __restrict__ n_iter_p,
                 float* __restrict__ out) {
  __shared__ __align__(16) float part[4 * 32 * 68];  // 34 KB [kq][row][m]
  __shared__ __align__(16) unsigned rs[2 * 32 * 32]; // 8 KB [plane][row][32u32], XOR

  const int t = threadIdx.x, wv = t >> 6, lane = t & 63;
  const int l31 = lane & 31, h = lane >> 5;   // 32x32 lane mapping
  const int lhi = lane >> 4, llo = lane & 15; // 16x16 lane mapping
  const int R0 = blockIdx.x * 32;
  const int n_iter = n_iter_p[0];
  const bool lowhalf = (l31 < 16);

  // ---- MV1 A-frags (32x32): GA[mt][ks] = G[32mt + l31][64wv + 16ks + 8h + j]
  short8 GAh[2][4], GAl[2][4];
#pragma unroll
  for (int mt = 0; mt < 2; ++mt)
#pragma unroll
    for (int ks = 0; ks < 4; ++ks) {
      const float* gp = &Gg[(32 * mt + l31) * 256 + 64 * wv + 16 * ks + 8 * h];
      split2x4(*(const f32x4*)gp, *(const f32x4*)(gp + 4), GAh[mt][ks], GAl[mt][ks]);
    }
  // ---- MV2 A-frags (16x16): GB[td][ks2] = G[32ks2 + 8lhi + j][64wv + 16td + llo]
  short8 GBh[4][2], GBl[4][2];
#pragma unroll
  for (int td = 0; td < 4; ++td)
#pragma unroll
    for (int ks2 = 0; ks2 < 2; ++ks2) {
      f32x4 fa, fb;
#pragma unroll
      for (int j = 0; j < 4; ++j) {
        fa[j] = Gg[(32 * ks2 + 8 * lhi + j) * 256 + 64 * wv + 16 * td + llo];
        fb[j] = Gg[(32 * ks2 + 8 * lhi + 4 + j) * 256 + 64 * wv + 16 * td + llo];
      }
      split2x4(fa, fb, GBh[td][ks2], GBl[td][ks2]);
    }

  // ---- bounds (z layout) / b' (reduce layout) ----
  f32x4 lbr[4], ubr[4];
#pragma unroll
  for (int td = 0; td < 4; ++td) {
    lbr[td] = *(const f32x4*)&lb[64 * wv + 16 * td + 4 * lhi];
    ubr[td] = *(const f32x4*)&ub[64 * wv + 16 * td + 4 * lhi];
  }
  const int rrow = t >> 3, m8 = (t & 7) * 8;
  f32x4 bpr0 = *(const f32x4*)&bpg[(R0 + rrow) * 64 + m8];
  f32x4 bpr1 = *(const f32x4*)&bpg[(R0 + rrow) * 64 + m8 + 4];

  // ---- precomputed LDS byte addresses ----
  const int pbase = ((wv * 32 + l31) * 68 + 4 * h) * 4;      // partial store base
  const int prd = (rrow * 68 + m8) * 4;                      // reduce read base
  const int rwr = rrow * 128 + 16 * ((t & 7) ^ (rrow & 7));  // rs write
  int rrd[2][2];  // MV2 rs read
  {
    int r3 = llo & 7;
#pragma unroll
    for (int tr = 0; tr < 2; ++tr)
#pragma unroll
      for (int ks2 = 0; ks2 < 2; ++ks2)
        rrd[tr][ks2] = (16 * tr + llo) * 128 + 16 * ((4 * ks2 + lhi) ^ r3);
  }

  // ---- z init (w is derived in-register each iteration) ----
  f32x4 z[4][2];
#pragma unroll
  for (int tr = 0; tr < 2; ++tr)
#pragma unroll
    for (int td = 0; td < 4; ++td)
      z[td][tr] = *(const f32x4*)&y0[(R0 + 16 * tr + llo) * 256 + 64 * wv + 16 * td + 4 * lhi];

  // phase-stagger the two co-resident blocks toward anti-alignment (~3.5k cyc)
  if (blockIdx.x & 1) {
#pragma unroll
    for (int s = 0; s < 7; ++s) __builtin_amdgcn_s_sleep(8);
  }

  for (int it = 0; it <= n_iter; ++it) {
    const bool wlast = (it == n_iter);

    // ---- MV1: partial r^T = G @ w^T over this wave's own k-quarter ----
    // w built from z in regs; cross-row quad exchange via ds_swizzle lane^16.
    f32x16 acc0 = {}, acc1 = {};
#pragma unroll
    for (int ks = 0; ks < 4; ++ks) {
      f32x4 w0, w1, ex, rc, f0, f1;
#pragma unroll
      for (int e = 0; e < 4; ++e) {
        float z0 = z[ks][0][e], z1 = z[ks][1][e];
        float p0 = med3(z0, lbr[ks][e], ubr[ks][e]);
        float p1 = med3(z1, lbr[ks][e], ubr[ks][e]);
        w0[e] = wlast ? p0 : fmaf(2.f, p0, -z0);
        w1[e] = wlast ? p1 : fmaf(2.f, p1, -z1);
        ex[e] = lowhalf ? w1[e] : w0[e];
      }
#pragma unroll
      for (int e = 0; e < 4; ++e)
        rc[e] = __uint_as_float(
            __builtin_amdgcn_ds_swizzle(__float_as_uint(ex[e]), 0x401F));  // xor 16
#pragma unroll
      for (int e = 0; e < 4; ++e) {
        f0[e] = lowhalf ? w0[e] : rc[e];
        f1[e] = lowhalf ? rc[e] : w1[e];
      }
      short8 Bh, Bl;
      split2x4(f0, f1, Bh, Bl);
      __builtin_amdgcn_s_setprio(1);
      acc0 = mfma32(GAh[0][ks], Bh, acc0);
      acc0 = mfma32(GAh[0][ks], Bl, acc0);
      acc0 = mfma32(GAl[0][ks], Bh, acc0);
      acc1 = mfma32(GAh[1][ks], Bh, acc1);
      acc1 = mfma32(GAh[1][ks], Bl, acc1);
      acc1 = mfma32(GAl[1][ks], Bh, acc1);
      __builtin_amdgcn_s_setprio(0);
    }
#pragma unroll
    for (int u = 0; u < 4; ++u) {
      f32x4 q0 = {acc0[4 * u], acc0[4 * u + 1], acc0[4 * u + 2], acc0[4 * u + 3]};
      f32x4 q1 = {acc1[4 * u], acc1[4 * u + 1], acc1[4 * u + 2], acc1[4 * u + 3]};
      *(f32x4*)((char*)part + (pbase + 32 * u)) = q0;
      *(f32x4*)((char*)part + (pbase + 32 * u + 128)) = q1;
    }
    __syncthreads();

    // ---- reduce 4 k-partials, -b', pack to bf16 hi/lo planes ----
    {
      const char* pb = (const char*)part + prd;
      f32x4 s0 = *(const f32x4*)pb;
      f32x4 s1 = *(const f32x4*)(pb + 16);
      s0 += *(const f32x4*)(pb + 8704);  s1 += *(const f32x4*)(pb + 8720);
      s0 += *(const f32x4*)(pb + 17408); s1 += *(const f32x4*)(pb + 17424);
      s0 += *(const f32x4*)(pb + 26112); s1 += *(const f32x4*)(pb + 26128);
      s0 -= bpr0; s1 -= bpr1;
      u32x4 hi4 = {pack_hi(s0[0], s0[1]), pack_hi(s0[2], s0[3]),
                   pack_hi(s1[0], s1[1]), pack_hi(s1[2], s1[3])};
      float l0 = s0[0] - trunch(s0[0]), l1 = s0[1] - trunch(s0[1]);
      float l2 = s0[2] - trunch(s0[2]), l3 = s0[3] - trunch(s0[3]);
      float l4 = s1[0] - trunch(s1[0]), l5 = s1[1] - trunch(s1[1]);
      float l6 = s1[2] - trunch(s1[2]), l7 = s1[3] - trunch(s1[3]);
      u32x4 lo4 = {pack_hi(l0, l1), pack_hi(l2, l3), pack_hi(l4, l5), pack_hi(l6, l7)};
      *(u32x4*)((char*)rs + rwr) = hi4;
      *(u32x4*)((char*)rs + (rwr + 4096)) = lo4;
    }
    __syncthreads();

    // ---- MV2: corr^T = G^T @ r^T (16x16), fused z-update / final store ----
#pragma unroll
    for (int tr = 0; tr < 2; ++tr) {
      short8 Rh[2], Rl[2];
#pragma unroll
      for (int ks2 = 0; ks2 < 2; ++ks2) {
        Rh[ks2] = *(const short8*)((const char*)rs + rrd[tr][ks2]);
        Rl[ks2] = *(const short8*)((const char*)rs + (rrd[tr][ks2] + 4096));
      }
      f32x4 c[4];
      __builtin_amdgcn_s_setprio(1);
#pragma unroll
      for (int td = 0; td < 4; ++td) {
        f32x4 cc = {};
        cc = mfma16(GBh[td][0], Rh[0], cc);
        cc = mfma16(GBh[td][0], Rl[0], cc);
        cc = mfma16(GBl[td][0], Rh[0], cc);
        cc = mfma16(GBh[td][1], Rh[1], cc);
        cc = mfma16(GBh[td][1], Rl[1], cc);
        cc = mfma16(GBl[td][1], Rh[1], cc);
        c[td] = cc;
      }
      __builtin_amdgcn_s_setprio(0);

      if (!wlast) {
#pragma unroll
        for (int td = 0; td < 4; ++td) {
          f32x4 zz = z[td][tr], zn;
#pragma unroll
          for (int e = 0; e < 4; ++e) {
            float p = med3(zz[e], lbr[td][e], ubr[td][e]);
            zn[e] = fmaf(1.7f, p - zz[e] - c[td][e], zz[e]);
          }
          z[td][tr] = zn;
        }
      } else {
#pragma unroll
        for (int td = 0; td < 4; ++td) {
          f32x4 zz = z[td][tr], o;
#pragma unroll
          for (int e = 0; e < 4; ++e) {
            float p = med3(zz[e], lbr[td][e], ubr[td][e]);
            o[e] = p - c[td][e];
          }
          *(f32x4*)&out[(R0 + 16 * tr + llo) * 256 + 64 * wv + 16 * td + 4 * lhi] = o;
        }
      }
    }
  }
}

// ---------------------------------------------------------------------------
extern "C" void kernel_launch(void* const* d_in, const int* in_sizes, int n_in,
                              void* d_out, int out_size, void* d_ws, size_t ws_size,
                              hipStream_t stream) {
  (void)in_sizes; (void)n_in; (void)out_size; (void)ws_size;
  const float* x  = (const float*)d_in[0];
  const float* bM = (const float*)d_in[1];
  const float* W1 = (const float*)d_in[2];
  const float* b1 = (const float*)d_in[3];
  const float* W2 = (const float*)d_in[4];
  const float* b2 = (const float*)d_in[5];
  const float* W3 = (const float*)d_in[6];
  const float* b3 = (const float*)d_in[7];
  const float* A  = (const float*)d_in[8];
  const float* lb = (const float*)d_in[9];
  const float* ub = (const float*)d_in[10];
  const int* n_iter = (const int*)d_in[11];
  float* out = (float*)d_out;

  float* ws = (float*)d_ws;
  float* y     = ws;                    // 16384*256
  float* h1    = ws;                    // 16384*200 (overlays y; dead before y)
  float* h2    = y + 16384 * 256;       // 16384*200
  float* bp    = h2 + 16384 * 200;      // 16384*64
  float* G     = bp + 16384 * 64;       // 64*256
  float* LinvT = G + 64 * 256;          // 64*64

  hipLaunchKernelGGL(prep_kernel, dim3(1), dim3(512), 0, stream, A, G, LinvT);
  hipLaunchKernelGGL(gemm64, dim3(256, 1), dim3(256), 0, stream, bM, LinvT, (const float*)nullptr, bp, 64, 64, 0);
  hipLaunchKernelGGL(gemm64, dim3(256, 2), dim3(256), 0, stream, x,  W1, b1, h1, 200, 256, 1);
  hipLaunchKernelGGL(gemm64, dim3(256, 2), dim3(256), 0, stream, h1, W2, b2, h2, 200, 200, 1);
  hipLaunchKernelGGL(gemm64, dim3(256, 2), dim3(256), 0, stream, h2, W3, b3, y,  256, 200, 0);
  hipLaunchKernelGGL(iter_kernel, dim3(512), dim3(256), 0, stream, y, G, bp, lb, ub, n_iter, out);
}